// Round 15
// baseline (95.855 us; speedup 1.0000x reference)
//
#include <hip/hip_runtime.h>
#include <math.h>

#define NQ   10
#define NLAY 4
#define BATCH 4096
#define HID  32
#define NM   20   // 2*NQ

typedef float    f2  __attribute__((ext_vector_type(2)));
typedef unsigned u2v __attribute__((ext_vector_type(2)));

// ---------------------------------------------------------------------------
// GF(2) tracking of the CNOT ring + a CHANGE OF STORAGE BASIS.
// Logical masks use wire w at bit (9-w). Storage basis: s = T x with
//   storage bit j (j=0..8) <-> d_j = b_j ^ b_{j+1},  storage bit 9 <-> b_9.
// Transforms (prefix-parity structure):
//   pair mask:  v'_j = parity(v, wires <= j) (j=0..8), v'_9 = parity(all)
//   row mask:   m'_j = m_j ^ m_{j+1} (j=0..8),          m'_9 = m_9
// Storage layout: s = (halfLane << 5) | reg.  reg bits = storage 0..4,
// lane bits = storage 5..9.  12/30 gates land entirely in reg bits (free),
// 13 on DPP, only 5 on the DS pipe.  Validated exact in R14 (same absmax).
// ---------------------------------------------------------------------------
struct Tables {
    unsigned col[NLAY + 1][NQ];
    unsigned row[NLAY + 1][NQ];
};

constexpr unsigned tr_col(unsigned v) {
    unsigned s = 0, pref = 0;
    for (int j = 0; j < 9; ++j) { pref ^= (v >> (9 - j)) & 1u; s |= pref << j; }
    unsigned tot = pref ^ (v & 1u);      // add wire 9 -> total parity
    s |= tot << 9;
    return s;
}
constexpr unsigned tr_row(unsigned m) {
    unsigned s = 0;
    for (int j = 0; j < 9; ++j) {
        unsigned a = (m >> (9 - j)) & 1u;   // wire j
        unsigned b = (m >> (8 - j)) & 1u;   // wire j+1
        s |= (a ^ b) << j;
    }
    s |= (m & 1u) << 9;                     // wire 9
    return s;
}

constexpr Tables make_tables() {
    Tables t{};
    unsigned col[NQ] = {}, row[NQ] = {};
    for (int k = 0; k < NQ; ++k) { col[k] = 1u << (NQ - 1 - k); row[k] = 1u << (NQ - 1 - k); }
    for (int l = 0; l <= NLAY; ++l) {
        for (int k = 0; k < NQ; ++k) { t.col[l][k] = col[k]; t.row[l][k] = row[k]; }
        for (int k = 0; k < NQ; ++k) {            // ring: CNOT(k, (k+1)%NQ)
            int c = k, tg = (k + 1) % NQ;
            col[c] ^= col[tg];
            row[tg] ^= row[c];
        }
    }
    for (int l = 0; l <= NLAY; ++l)
        for (int k = 0; k < NQ; ++k) {
            t.col[l][k] = tr_col(t.col[l][k]);
            t.row[l][k] = tr_row(t.row[l][k]);
        }
    return t;
}

static constexpr Tables TB = make_tables();

struct cpx { float x, y; };
__device__ __forceinline__ cpx cxmul(cpx a, cpx b) {
    return { fmaf(a.x, b.x, -a.y * b.y), fmaf(a.x, b.y, a.y * b.x) };
}

__device__ __forceinline__ f2 mk2(float a, float b) { f2 r; r[0] = a; r[1] = b; return r; }
__device__ __forceinline__ f2 ffma(f2 a, f2 b, f2 c) { return __builtin_elementwise_fma(a, b, c); }

// acc += a (*) b   complex, interleaved (re,im) per f2 (VOP3P-foldable shapes).
__device__ __forceinline__ f2 cmac(f2 acc, f2 a, f2 b) {
    acc = ffma(mk2(a[0], a[0]), b, acc);
    acc = ffma(mk2(-a[1], a[1]), mk2(b[1], b[0]), acc);
    return acc;
}

// ---- DPP lane-xor within a 16-lane row (VALU pipe) ------------------------
template<int CTRL>
__device__ __forceinline__ float dppf(float x) {
    return __int_as_float(__builtin_amdgcn_update_dpp(
        0, __float_as_int(x), CTRL, 0xF, 0xF, true));
}

template<unsigned M>
__device__ __forceinline__ float dpplo(float x) {
    static_assert(M < 16u, "dpplo handles masks 0..15");
    if constexpr (M == 0u)       return x;
    else if constexpr (M == 1u)  return dppf<0xB1>(x);                 // quad_perm [1,0,3,2]
    else if constexpr (M == 2u)  return dppf<0x4E>(x);                 // quad_perm [2,3,0,1]
    else if constexpr (M == 3u)  return dppf<0x1B>(x);                 // quad_perm [3,2,1,0]
    else if constexpr (M == 7u)  return dppf<0x141>(x);                // row_half_mirror
    else if constexpr (M == 8u)  return dppf<0x128>(x);                // row_ror:8
    else if constexpr (M == 15u) return dppf<0x140>(x);                // row_mirror
    else if constexpr (M == 4u)  return dppf<0x141>(dppf<0x1B>(x));    // 7^3
    else if constexpr (M == 5u)  return dppf<0x141>(dppf<0x4E>(x));    // 7^2
    else if constexpr (M == 6u)  return dppf<0x141>(dppf<0xB1>(x));    // 7^1
    else if constexpr (M == 9u)  return dppf<0x128>(dppf<0xB1>(x));    // 8^1
    else if constexpr (M == 10u) return dppf<0x128>(dppf<0x4E>(x));    // 8^2
    else if constexpr (M == 11u) return dppf<0x128>(dppf<0x1B>(x));    // 8^3
    else if constexpr (M == 12u) return dppf<0x140>(dppf<0x1B>(x));    // 15^3
    else if constexpr (M == 13u) return dppf<0x140>(dppf<0x4E>(x));    // 15^2
    else                         return dppf<0x140>(dppf<0xB1>(x));    // 14 = 15^1
}

// x + x^16 fold (convention-independent permlane16_swap; within a 32-half)
__device__ __forceinline__ float redfold16(float x) {
#if __has_builtin(__builtin_amdgcn_permlane16_swap)
    u2v r = __builtin_amdgcn_permlane16_swap(__float_as_uint(x), __float_as_uint(x), false, false);
    return __uint_as_float(r[0]) + __uint_as_float(r[1]);
#else
    return x + __shfl_xor(x, 16);
#endif
}

// lane-xor by compile-time MASK (MASK <= 31, never crosses the half):
// bit 4 present -> ONE ds_swizzle (BitMode, compile-time offset, zero VALU);
// bits 0..3 only -> DPP on the VALU pipe.
template<unsigned M>
__device__ __forceinline__ float xlane(float x) {
    if constexpr (M == 0u) return x;
    else if constexpr ((M & 16u) != 0u)
        return __int_as_float(__builtin_amdgcn_ds_swizzle(
            __float_as_int(x), (int)((M << 10) | 0x1F)));   // xor within 32 lanes
    else return dpplo<M>(x);                                // VALU pipe
}

// ---- one single-qubit gate, 32 amps/lane, pair-local (low liveness) -------
template<int L, int K>
__device__ __forceinline__ void apply_gate(f2 (&st)[32], const float4 (*gm)[2],
                                           const int lane) {
    constexpr unsigned v     = TB.col[L][K];
    constexpr unsigned m     = TB.row[L][K];
    constexpr unsigned vlane = (v >> 5) & 31u;
    constexpr int      vr    = (int)(v & 31u);
    constexpr unsigned mlane = (m >> 5) & 31u;
    constexpr int      mr    = (int)(m & 31u);
    constexpr int      gi    = L * NQ + K;

    int laneP = 0;
    if constexpr (mlane != 0u) laneP = __popc((unsigned)lane & mlane) & 1;
    const float4 A = gm[gi][laneP];
    const f2 ocA = mk2(A.x, A.y), pcA = mk2(A.z, A.w);
    f2 ocB = ocA, pcB = pcA;
    if constexpr (mr != 0) {
        const float4 B = gm[gi][laneP ^ 1];
        ocB = mk2(B.x, B.y); pcB = mk2(B.z, B.w);
    }

    // pair-local processing keeps liveness minimal (~80 VGPRs total)
    #pragma unroll
    for (int r = 0; r < 32; ++r) {
        const int r2 = r ^ vr;
        if (r2 < r) continue;
        f2 p_r, p_r2;
        if constexpr (vlane != 0u) {
            p_r = mk2(xlane<vlane>(st[r2][0]), xlane<vlane>(st[r2][1]));
            if (r2 != r)
                p_r2 = mk2(xlane<vlane>(st[r][0]), xlane<vlane>(st[r][1]));
        } else {
            p_r = st[r2];
            p_r2 = st[r];
        }
        {
            const int pr = __builtin_popcount((unsigned)(r & mr)) & 1;
            const f2 oc = pr ? ocB : ocA;
            const f2 pc = pr ? pcB : pcA;
            f2 acc = mk2(0.f, 0.f);
            acc = cmac(acc, oc, st[r]);
            acc = cmac(acc, pc, p_r);
            if (r2 != r) {
                const int pr2 = __builtin_popcount((unsigned)(r2 & mr)) & 1;
                const f2 oc2 = pr2 ? ocB : ocA;
                const f2 pc2 = pr2 ? pcB : pcA;
                f2 acc2 = mk2(0.f, 0.f);
                acc2 = cmac(acc2, oc2, st[r2]);
                acc2 = cmac(acc2, pc2, p_r2);
                st[r2] = acc2;
            }
            st[r] = acc;
        }
    }
}

// One block = 256 threads = 4 waves = 8 batch elements (2 per wave, one per
// 32-lane half). No barriers in the gate loop; grid = BATCH/8 = 512 blocks.
__global__ __launch_bounds__(256, 2)
void qrh_kernel(
    const float* __restrict__ theta, const float* __restrict__ rotw,
    const float* __restrict__ escale, const float* __restrict__ ebias,
    const float* __restrict__ W1, const float* __restrict__ b1,
    const float* __restrict__ W2, const float* __restrict__ b2,
    float* __restrict__ out)
{
    // per element, per gate: group0=[U00,U01], group1=[U11,U10]
    __shared__ float4 gmat[8 * NLAY * NQ][2];
    __shared__ float4 wtab[8][NQ];   // layer-0 product vectors per element

    const int tid  = threadIdx.x;
    const int lane = tid & 63;
    const int wv   = tid >> 6;
    const int e    = (wv << 1) | (lane >> 5);   // element in block 0..7
    const int b    = blockIdx.x * 8 + e;

    // ---- per-gate 2x2 unitary, thread-parallel over 8*40 = 320 gates ----
    for (int g = tid; g < 8 * NLAY * NQ; g += 256) {
        const int ge = g / (NLAY * NQ);       // element 0..7
        const int gg = g % (NLAY * NQ);
        const int l = gg / NQ, k = gg % NQ;
        const int gb = blockIdx.x * 8 + ge;
        const float th = theta[gb * NQ + k];
        const int e2 = (l * NQ + k) * 2;
        const float t0 = escale[e2 + 0] * th + ebias[e2 + 0];
        const float t1 = escale[e2 + 1] * th + ebias[e2 + 1];
        float sn0, c0, sn1, c1;
        __sincosf(0.5f * t0, &sn0, &c0);
        __sincosf(0.5f * t1, &sn1, &c1);
        // U_enc = RX(t1) RZ(t0)
        const f2 E00 = mk2( c1 * c0,  -c1 * sn0);
        const f2 E01 = mk2( sn1 * sn0, -sn1 * c0);
        const f2 E10 = mk2(-sn1 * sn0, -sn1 * c0);
        const f2 E11 = mk2( c1 * c0,   c1 * sn0);
        const int r3 = (l * NQ + k) * 3;
        const float w0 = rotw[r3 + 0], w1 = rotw[r3 + 1], w2 = rotw[r3 + 2];
        float cw, sw, ca0, sa0, ca1, sa1;
        __sincosf(0.5f * w1, &sw, &cw);
        __sincosf(0.5f * (w0 + w2), &sa0, &ca0);
        __sincosf(0.5f * (w0 - w2), &sa1, &ca1);
        // U_rot = RZ(w2) RY(w1) RZ(w0)
        const f2 R00 = mk2( cw * ca0, -cw * sa0);
        const f2 R01 = mk2(-sw * ca1, -sw * sa1);
        const f2 R10 = mk2( sw * ca1, -sw * sa1);
        const f2 R11 = mk2( cw * ca0,  cw * sa0);
        auto cm = [](f2 a, f2 bb) { return mk2(a[0]*bb[0] - a[1]*bb[1], a[0]*bb[1] + a[1]*bb[0]); };
        const f2 U00 = cm(R00, E00) + cm(R01, E10);
        const f2 U01 = cm(R00, E01) + cm(R01, E11);
        const f2 U10 = cm(R10, E00) + cm(R11, E10);
        const f2 U11 = cm(R10, E01) + cm(R11, E11);
        gmat[g][0] = make_float4(U00[0], U00[1], U01[0], U01[1]);
        gmat[g][1] = make_float4(U11[0], U11[1], U10[0], U10[1]);
        if (l == 0) {
            // layer-0 acts on |+>^10: per-wire 2-vector w = U*(1,1)/sqrt(2)
            const float inv = 0.70710678118654752f;
            const f2 al = (U00 + U01) * inv;
            const f2 be = (U10 + U11) * inv;
            wtab[ge][k] = make_float4(al[0], al[1], be[0], be[1]);
        }
    }
    __syncthreads();

    // ---- de-synchronize DS bursts: odd waves start the gate pipeline late.
    if (wv & 1) { __builtin_amdgcn_s_sleep(10); __builtin_amdgcn_s_sleep(10); }

    // ---- layer-0 product state in the TRANSFORMED basis -------------------
    // x_0=r0, x_1=r0^r1, x_2=r1^r2, x_3=r2^r3, x_4=r3^r4,
    // x_5=r4^h0, x_6=h0^h1, x_7=h1^h2, x_8=h2^h3, x_9=h3^h4
    const int hl = lane & 31;
    f2 st[32];
    {
        cpx w_[10][2];
        #pragma unroll
        for (int k = 0; k < NQ; ++k) {
            const float4 q = wtab[e][k];
            w_[k][0] = {q.x, q.y};
            w_[k][1] = {q.z, q.w};
        }
        const int h0 = hl & 1, h1 = (hl >> 1) & 1, h2 = (hl >> 2) & 1,
                  h3 = (hl >> 3) & 1, h4 = (hl >> 4) & 1;
        const cpx PL = cxmul(cxmul(w_[6][h0 ^ h1], w_[7][h1 ^ h2]),
                             cxmul(w_[8][h2 ^ h3], w_[9][h3 ^ h4]));
        const cpx PL5[2] = { cxmul(PL, w_[5][h0]), cxmul(PL, w_[5][1 ^ h0]) };
        cpx G012[8], G34[8];
        #pragma unroll
        for (int q = 0; q < 8; ++q) {
            const int a0 = q & 1, a1 = (q >> 1) & 1, a2 = (q >> 2) & 1;
            G012[q] = cxmul(cxmul(w_[0][a0], w_[1][a0 ^ a1]), w_[2][a1 ^ a2]);
            G34[q]  = cxmul(w_[3][a0 ^ a1], w_[4][a1 ^ a2]);   // keyed (r2,r3,r4)
        }
        #pragma unroll
        for (int r = 0; r < 32; ++r) {
            const cpx g = cxmul(G012[r & 7], G34[(r >> 2) & 7]);
            const cpx t = cxmul(PL5[(r >> 4) & 1], g);
            st[r] = mk2(t.x, t.y);
        }
    }

    const float4 (*gm)[2] = &gmat[e * NLAY * NQ];

    #define GATE(L,K) apply_gate<L,K>(st, gm, lane);
    #define LAYER(L) GATE(L,0) GATE(L,1) GATE(L,2) GATE(L,3) GATE(L,4) \
                     GATE(L,5) GATE(L,6) GATE(L,7) GATE(L,8) GATE(L,9)
    LAYER(1)
    LAYER(2)
    LAYER(3)
    #undef LAYER
    #undef GATE

    // ---- measurement: probs then 5-bit FWHT over register index ----
    float w[32];
    #pragma unroll
    for (int r = 0; r < 32; ++r) {
        const f2 sq = st[r] * st[r];
        w[r] = sq[0] + sq[1];
    }
    #pragma unroll
    for (int bit = 1; bit < 32; bit <<= 1) {
        #pragma unroll
        for (int j = 0; j < 32; ++j) {
            if (!(j & bit)) {
                const float a = w[j], c = w[j | bit];
                w[j] = a + c; w[j | bit] = a - c;
            }
        }
    }
    // w[t] = sum_r (-1)^{popc(r&t)} p[r]

    float feats[NM];
    #pragma unroll
    for (int f = 0; f < NM; ++f) {
        const unsigned M = (f < NQ) ? TB.row[NLAY][f]
                                    : (TB.row[NLAY][f - NQ] ^ TB.row[NLAY][(f - NQ + 1) % NQ]);
        const unsigned Mlane = (M >> 5) & 31u;
        const int Mr = (int)(M & 31u);
        const float s = w[Mr];
        const int lsgn = __popc((unsigned)lane & Mlane) & 1;
        feats[f] = lsgn ? -s : s;
    }
    // reduction within the 32-lane half over basis masks {1,2,7,8,16}
    #pragma unroll
    for (int f = 0; f < NM; ++f) {
        float v = feats[f];
        v += dppf<0xB1>(v);    // ^1
        v += dppf<0x4E>(v);    // ^2
        v += dppf<0x141>(v);   // ^7
        v += dppf<0x128>(v);   // ^8
        v = redfold16(v);      // ^16
        feats[f] = v;
    }

    // ---- MLP head: each lane of the half computes one hidden unit ----
    float part;
    {
        float acc = b1[hl];
        #pragma unroll
        for (int mm = 0; mm < NM; ++mm) acc = fmaf(feats[mm], W1[hl * NM + mm], acc);
        const float sg = 1.f / (1.f + __expf(-acc));
        part = acc * sg * W2[hl];
    }
    part += dppf<0xB1>(part);
    part += dppf<0x4E>(part);
    part += dppf<0x141>(part);
    part += dppf<0x128>(part);
    part = redfold16(part);
    if (hl == 0) out[b] = part + b2[0];
}

extern "C" void kernel_launch(void* const* d_in, const int* in_sizes, int n_in,
                              void* d_out, int out_size, void* d_ws, size_t ws_size,
                              hipStream_t stream) {
    (void)in_sizes; (void)n_in; (void)out_size; (void)d_ws; (void)ws_size;
    const float* theta = (const float*)d_in[0];
    const float* rotw  = (const float*)d_in[1];
    const float* esc   = (const float*)d_in[2];
    const float* ebi   = (const float*)d_in[3];
    const float* W1    = (const float*)d_in[4];
    const float* b1    = (const float*)d_in[5];
    const float* W2    = (const float*)d_in[6];
    const float* b2    = (const float*)d_in[7];
    float* out = (float*)d_out;

    qrh_kernel<<<BATCH / 8, 256, 0, stream>>>(theta, rotw, esc, ebi, W1, b1, W2, b2, out);
}

// Round 16
// 92.675 us; speedup vs baseline: 1.0343x; 1.0343x over previous
//
#include <hip/hip_runtime.h>
#include <math.h>

#define NQ   10
#define NLAY 4
#define BATCH 4096
#define HID  32
#define NM   20   // 2*NQ

typedef float    f2  __attribute__((ext_vector_type(2)));
typedef unsigned u2v __attribute__((ext_vector_type(2)));

// ---------------------------------------------------------------------------
// GF(2) tracking of the CNOT ring + a CHANGE OF STORAGE BASIS.
// Logical masks use wire w at bit (9-w). Storage basis: s = T x with
//   storage bit j (j=0..8) <-> d_j = b_j ^ b_{j+1},  storage bit 9 <-> b_9.
// Transforms (prefix-parity structure):
//   pair mask:  v'_j = parity(v, wires <= j) (j=0..8), v'_9 = parity(all)
//   row mask:   m'_j = m_j ^ m_{j+1} (j=0..8),          m'_9 = m_9
// Storage layout: s = (halfLane << 5) | reg.  reg bits = storage 0..4,
// lane bits = storage 5..9.  12/30 gates land entirely in reg bits (free),
// 13 on DPP, only 5 on the DS pipe.  Validated exact in R14/R15 (same absmax).
// ---------------------------------------------------------------------------
struct Tables {
    unsigned col[NLAY + 1][NQ];
    unsigned row[NLAY + 1][NQ];
};

constexpr unsigned tr_col(unsigned v) {
    unsigned s = 0, pref = 0;
    for (int j = 0; j < 9; ++j) { pref ^= (v >> (9 - j)) & 1u; s |= pref << j; }
    unsigned tot = pref ^ (v & 1u);      // add wire 9 -> total parity
    s |= tot << 9;
    return s;
}
constexpr unsigned tr_row(unsigned m) {
    unsigned s = 0;
    for (int j = 0; j < 9; ++j) {
        unsigned a = (m >> (9 - j)) & 1u;   // wire j
        unsigned b = (m >> (8 - j)) & 1u;   // wire j+1
        s |= (a ^ b) << j;
    }
    s |= (m & 1u) << 9;                     // wire 9
    return s;
}

constexpr Tables make_tables() {
    Tables t{};
    unsigned col[NQ] = {}, row[NQ] = {};
    for (int k = 0; k < NQ; ++k) { col[k] = 1u << (NQ - 1 - k); row[k] = 1u << (NQ - 1 - k); }
    for (int l = 0; l <= NLAY; ++l) {
        for (int k = 0; k < NQ; ++k) { t.col[l][k] = col[k]; t.row[l][k] = row[k]; }
        for (int k = 0; k < NQ; ++k) {            // ring: CNOT(k, (k+1)%NQ)
            int c = k, tg = (k + 1) % NQ;
            col[c] ^= col[tg];
            row[tg] ^= row[c];
        }
    }
    for (int l = 0; l <= NLAY; ++l)
        for (int k = 0; k < NQ; ++k) {
            t.col[l][k] = tr_col(t.col[l][k]);
            t.row[l][k] = tr_row(t.row[l][k]);
        }
    return t;
}

static constexpr Tables TB = make_tables();

struct cpx { float x, y; };
__device__ __forceinline__ cpx cxmul(cpx a, cpx b) {
    return { fmaf(a.x, b.x, -a.y * b.y), fmaf(a.x, b.y, a.y * b.x) };
}

__device__ __forceinline__ f2 mk2(float a, float b) { f2 r; r[0] = a; r[1] = b; return r; }
__device__ __forceinline__ f2 ffma(f2 a, f2 b, f2 c) { return __builtin_elementwise_fma(a, b, c); }

// acc += a (*) b   complex, interleaved (re,im) per f2 (VOP3P-foldable shapes).
__device__ __forceinline__ f2 cmac(f2 acc, f2 a, f2 b) {
    acc = ffma(mk2(a[0], a[0]), b, acc);
    acc = ffma(mk2(-a[1], a[1]), mk2(b[1], b[0]), acc);
    return acc;
}

// ---- DPP lane-xor within a 16-lane row (VALU pipe) ------------------------
template<int CTRL>
__device__ __forceinline__ float dppf(float x) {
    return __int_as_float(__builtin_amdgcn_update_dpp(
        0, __float_as_int(x), CTRL, 0xF, 0xF, true));
}

template<unsigned M>
__device__ __forceinline__ float dpplo(float x) {
    static_assert(M < 16u, "dpplo handles masks 0..15");
    if constexpr (M == 0u)       return x;
    else if constexpr (M == 1u)  return dppf<0xB1>(x);                 // quad_perm [1,0,3,2]
    else if constexpr (M == 2u)  return dppf<0x4E>(x);                 // quad_perm [2,3,0,1]
    else if constexpr (M == 3u)  return dppf<0x1B>(x);                 // quad_perm [3,2,1,0]
    else if constexpr (M == 7u)  return dppf<0x141>(x);                // row_half_mirror
    else if constexpr (M == 8u)  return dppf<0x128>(x);                // row_ror:8
    else if constexpr (M == 15u) return dppf<0x140>(x);                // row_mirror
    else if constexpr (M == 4u)  return dppf<0x141>(dppf<0x1B>(x));    // 7^3
    else if constexpr (M == 5u)  return dppf<0x141>(dppf<0x4E>(x));    // 7^2
    else if constexpr (M == 6u)  return dppf<0x141>(dppf<0xB1>(x));    // 7^1
    else if constexpr (M == 9u)  return dppf<0x128>(dppf<0xB1>(x));    // 8^1
    else if constexpr (M == 10u) return dppf<0x128>(dppf<0x4E>(x));    // 8^2
    else if constexpr (M == 11u) return dppf<0x128>(dppf<0x1B>(x));    // 8^3
    else if constexpr (M == 12u) return dppf<0x140>(dppf<0x1B>(x));    // 15^3
    else if constexpr (M == 13u) return dppf<0x140>(dppf<0x4E>(x));    // 15^2
    else                         return dppf<0x140>(dppf<0xB1>(x));    // 14 = 15^1
}

// x + x^16 fold (convention-independent permlane16_swap; within a 32-half)
__device__ __forceinline__ float redfold16(float x) {
#if __has_builtin(__builtin_amdgcn_permlane16_swap)
    u2v r = __builtin_amdgcn_permlane16_swap(__float_as_uint(x), __float_as_uint(x), false, false);
    return __uint_as_float(r[0]) + __uint_as_float(r[1]);
#else
    return x + __shfl_xor(x, 16);
#endif
}

// lane-xor by compile-time MASK (MASK <= 31, never crosses the half):
// bit 4 present -> ONE ds_swizzle (BitMode, compile-time offset, zero VALU);
// bits 0..3 only -> DPP on the VALU pipe.
template<unsigned M>
__device__ __forceinline__ float xlane(float x) {
    if constexpr (M == 0u) return x;
    else if constexpr ((M & 16u) != 0u)
        return __int_as_float(__builtin_amdgcn_ds_swizzle(
            __float_as_int(x), (int)((M << 10) | 0x1F)));   // xor within 32 lanes
    else return dpplo<M>(x);                                // VALU pipe
}

// ---- one single-qubit gate, 32 amps/lane, pair-local (low liveness) -------
template<int L, int K>
__device__ __forceinline__ void apply_gate(f2 (&st)[32], const float4 (*gm)[2],
                                           const int lane) {
    constexpr unsigned v     = TB.col[L][K];
    constexpr unsigned m     = TB.row[L][K];
    constexpr unsigned vlane = (v >> 5) & 31u;
    constexpr int      vr    = (int)(v & 31u);
    constexpr unsigned mlane = (m >> 5) & 31u;
    constexpr int      mr    = (int)(m & 31u);
    constexpr int      gi    = L * NQ + K;

    int laneP = 0;
    if constexpr (mlane != 0u) laneP = __popc((unsigned)lane & mlane) & 1;
    const float4 A = gm[gi][laneP];
    const f2 ocA = mk2(A.x, A.y), pcA = mk2(A.z, A.w);
    f2 ocB = ocA, pcB = pcA;
    if constexpr (mr != 0) {
        const float4 B = gm[gi][laneP ^ 1];
        ocB = mk2(B.x, B.y); pcB = mk2(B.z, B.w);
    }

    // pair-local processing keeps liveness minimal
    #pragma unroll
    for (int r = 0; r < 32; ++r) {
        const int r2 = r ^ vr;
        if (r2 < r) continue;
        f2 p_r, p_r2;
        if constexpr (vlane != 0u) {
            p_r = mk2(xlane<vlane>(st[r2][0]), xlane<vlane>(st[r2][1]));
            if (r2 != r)
                p_r2 = mk2(xlane<vlane>(st[r][0]), xlane<vlane>(st[r][1]));
        } else {
            p_r = st[r2];
            p_r2 = st[r];
        }
        {
            const int pr = __builtin_popcount((unsigned)(r & mr)) & 1;
            const f2 oc = pr ? ocB : ocA;
            const f2 pc = pr ? pcB : pcA;
            f2 acc = mk2(0.f, 0.f);
            acc = cmac(acc, oc, st[r]);
            acc = cmac(acc, pc, p_r);
            if (r2 != r) {
                const int pr2 = __builtin_popcount((unsigned)(r2 & mr)) & 1;
                const f2 oc2 = pr2 ? ocB : ocA;
                const f2 pc2 = pr2 ? pcB : pcA;
                f2 acc2 = mk2(0.f, 0.f);
                acc2 = cmac(acc2, oc2, st[r2]);
                acc2 = cmac(acc2, pc2, p_r2);
                st[r2] = acc2;
            }
            st[r] = acc;
        }
    }
}

// runtime-bit pick WITHOUT array indexing (stays in VGPRs: v_cndmask)
__device__ __forceinline__ cpx pick(const float4 q, int bit) {
    return { bit ? q.z : q.x, bit ? q.w : q.y };
}

// One block = 256 threads = 4 waves = 8 batch elements (2 per wave, one per
// 32-lane half). No barriers in the gate loop; grid = BATCH/8 = 512 blocks.
__global__ __launch_bounds__(256, 2)
void qrh_kernel(
    const float* __restrict__ theta, const float* __restrict__ rotw,
    const float* __restrict__ escale, const float* __restrict__ ebias,
    const float* __restrict__ W1, const float* __restrict__ b1,
    const float* __restrict__ W2, const float* __restrict__ b2,
    float* __restrict__ out)
{
    // per element, per gate: group0=[U00,U01], group1=[U11,U10]
    __shared__ float4 gmat[8 * NLAY * NQ][2];
    __shared__ float4 wtab[8][NQ];   // layer-0 product vectors per element

    const int tid  = threadIdx.x;
    const int lane = tid & 63;
    const int wv   = tid >> 6;
    const int e    = (wv << 1) | (lane >> 5);   // element in block 0..7
    const int b    = blockIdx.x * 8 + e;

    // ---- per-gate 2x2 unitary, thread-parallel over 8*40 = 320 gates ----
    for (int g = tid; g < 8 * NLAY * NQ; g += 256) {
        const int ge = g / (NLAY * NQ);       // element 0..7
        const int gg = g % (NLAY * NQ);
        const int l = gg / NQ, k = gg % NQ;
        const int gb = blockIdx.x * 8 + ge;
        const float th = theta[gb * NQ + k];
        const int e2 = (l * NQ + k) * 2;
        const float t0 = escale[e2 + 0] * th + ebias[e2 + 0];
        const float t1 = escale[e2 + 1] * th + ebias[e2 + 1];
        float sn0, c0, sn1, c1;
        __sincosf(0.5f * t0, &sn0, &c0);
        __sincosf(0.5f * t1, &sn1, &c1);
        // U_enc = RX(t1) RZ(t0)
        const f2 E00 = mk2( c1 * c0,  -c1 * sn0);
        const f2 E01 = mk2( sn1 * sn0, -sn1 * c0);
        const f2 E10 = mk2(-sn1 * sn0, -sn1 * c0);
        const f2 E11 = mk2( c1 * c0,   c1 * sn0);
        const int r3 = (l * NQ + k) * 3;
        const float w0 = rotw[r3 + 0], w1 = rotw[r3 + 1], w2 = rotw[r3 + 2];
        float cw, sw, ca0, sa0, ca1, sa1;
        __sincosf(0.5f * w1, &sw, &cw);
        __sincosf(0.5f * (w0 + w2), &sa0, &ca0);
        __sincosf(0.5f * (w0 - w2), &sa1, &ca1);
        // U_rot = RZ(w2) RY(w1) RZ(w0)
        const f2 R00 = mk2( cw * ca0, -cw * sa0);
        const f2 R01 = mk2(-sw * ca1, -sw * sa1);
        const f2 R10 = mk2( sw * ca1, -sw * sa1);
        const f2 R11 = mk2( cw * ca0,  cw * sa0);
        auto cm = [](f2 a, f2 bb) { return mk2(a[0]*bb[0] - a[1]*bb[1], a[0]*bb[1] + a[1]*bb[0]); };
        const f2 U00 = cm(R00, E00) + cm(R01, E10);
        const f2 U01 = cm(R00, E01) + cm(R01, E11);
        const f2 U10 = cm(R10, E00) + cm(R11, E10);
        const f2 U11 = cm(R10, E01) + cm(R11, E11);
        gmat[g][0] = make_float4(U00[0], U00[1], U01[0], U01[1]);
        gmat[g][1] = make_float4(U11[0], U11[1], U10[0], U10[1]);
        if (l == 0) {
            // layer-0 acts on |+>^10: per-wire 2-vector w = U*(1,1)/sqrt(2)
            const float inv = 0.70710678118654752f;
            const f2 al = (U00 + U01) * inv;
            const f2 be = (U10 + U11) * inv;
            wtab[ge][k] = make_float4(al[0], al[1], be[0], be[1]);
        }
    }
    __syncthreads();

    // ---- de-synchronize DS bursts: odd waves start the gate pipeline late.
    if (wv & 1) { __builtin_amdgcn_s_sleep(10); __builtin_amdgcn_s_sleep(10); }

    // ---- layer-0 product state in the TRANSFORMED basis -------------------
    // x_0=r0, x_1=r0^r1, x_2=r1^r2, x_3=r2^r3, x_4=r3^r4,
    // x_5=r4^h0, x_6=h0^h1, x_7=h1^h2, x_8=h2^h3, x_9=h3^h4
    // NOTE: all runtime-bit selections use pick() (cndmask) — NO runtime
    // array indexing (that was the 20 MB scratch spill in R14/R15).
    const int hl = lane & 31;
    f2 st[32];
    {
        const int h0 = hl & 1, h1 = (hl >> 1) & 1, h2 = (hl >> 2) & 1,
                  h3 = (hl >> 3) & 1, h4 = (hl >> 4) & 1;
        // lane-only part: wires 6..9 (runtime bits -> cndmask picks)
        const cpx W6 = pick(wtab[e][6], h0 ^ h1);
        const cpx W7 = pick(wtab[e][7], h1 ^ h2);
        const cpx W8 = pick(wtab[e][8], h2 ^ h3);
        const cpx W9 = pick(wtab[e][9], h3 ^ h4);
        const cpx PL = cxmul(cxmul(W6, W7), cxmul(W8, W9));
        // wire 5: x5 = r4 ^ h0 (r4 compile-time at use site)
        const float4 q5 = wtab[e][5];
        const cpx W5a = pick(q5, h0);        // r4 = 0
        const cpx W5b = pick(q5, 1 ^ h0);    // r4 = 1
        const cpx PL5[2] = { cxmul(PL, W5a), cxmul(PL, W5b) };
        // reg-only part: wires 0..4, all indices compile-time
        const float4 q0 = wtab[e][0], q1 = wtab[e][1], q2 = wtab[e][2];
        const float4 q3 = wtab[e][3], q4 = wtab[e][4];
        const cpx w0c[2] = {{q0.x, q0.y}, {q0.z, q0.w}};
        const cpx w1c[2] = {{q1.x, q1.y}, {q1.z, q1.w}};
        const cpx w2c[2] = {{q2.x, q2.y}, {q2.z, q2.w}};
        const cpx w3c[2] = {{q3.x, q3.y}, {q3.z, q3.w}};
        const cpx w4c[2] = {{q4.x, q4.y}, {q4.z, q4.w}};
        cpx G012[8], G34[8];
        #pragma unroll
        for (int q = 0; q < 8; ++q) {
            const int a0 = q & 1, a1 = (q >> 1) & 1, a2 = (q >> 2) & 1;
            G012[q] = cxmul(cxmul(w0c[a0], w1c[a0 ^ a1]), w2c[a1 ^ a2]);
            G34[q]  = cxmul(w3c[a0 ^ a1], w4c[a1 ^ a2]);   // keyed (r2,r3,r4)
        }
        #pragma unroll
        for (int r = 0; r < 32; ++r) {
            const cpx g = cxmul(G012[r & 7], G34[(r >> 2) & 7]);
            const cpx t = cxmul(PL5[(r >> 4) & 1], g);
            st[r] = mk2(t.x, t.y);
        }
    }

    const float4 (*gm)[2] = &gmat[e * NLAY * NQ];

    #define GATE(L,K) apply_gate<L,K>(st, gm, lane);
    #define LAYER(L) GATE(L,0) GATE(L,1) GATE(L,2) GATE(L,3) GATE(L,4) \
                     GATE(L,5) GATE(L,6) GATE(L,7) GATE(L,8) GATE(L,9)
    LAYER(1)
    LAYER(2)
    LAYER(3)
    #undef LAYER
    #undef GATE

    // ---- measurement: probs then 5-bit FWHT over register index ----
    float w[32];
    #pragma unroll
    for (int r = 0; r < 32; ++r) {
        const f2 sq = st[r] * st[r];
        w[r] = sq[0] + sq[1];
    }
    #pragma unroll
    for (int bit = 1; bit < 32; bit <<= 1) {
        #pragma unroll
        for (int j = 0; j < 32; ++j) {
            if (!(j & bit)) {
                const float a = w[j], c = w[j | bit];
                w[j] = a + c; w[j | bit] = a - c;
            }
        }
    }
    // w[t] = sum_r (-1)^{popc(r&t)} p[r]

    float feats[NM];
    #pragma unroll
    for (int f = 0; f < NM; ++f) {
        const unsigned M = (f < NQ) ? TB.row[NLAY][f]
                                    : (TB.row[NLAY][f - NQ] ^ TB.row[NLAY][(f - NQ + 1) % NQ]);
        const unsigned Mlane = (M >> 5) & 31u;
        const int Mr = (int)(M & 31u);
        const float s = w[Mr];
        const int lsgn = __popc((unsigned)lane & Mlane) & 1;
        feats[f] = lsgn ? -s : s;
    }
    // reduction within the 32-lane half over basis masks {1,2,7,8,16}
    #pragma unroll
    for (int f = 0; f < NM; ++f) {
        float v = feats[f];
        v += dppf<0xB1>(v);    // ^1
        v += dppf<0x4E>(v);    // ^2
        v += dppf<0x141>(v);   // ^7
        v += dppf<0x128>(v);   // ^8
        v = redfold16(v);      // ^16
        feats[f] = v;
    }

    // ---- MLP head: each lane of the half computes one hidden unit ----
    float part;
    {
        float acc = b1[hl];
        #pragma unroll
        for (int mm = 0; mm < NM; ++mm) acc = fmaf(feats[mm], W1[hl * NM + mm], acc);
        const float sg = 1.f / (1.f + __expf(-acc));
        part = acc * sg * W2[hl];
    }
    part += dppf<0xB1>(part);
    part += dppf<0x4E>(part);
    part += dppf<0x141>(part);
    part += dppf<0x128>(part);
    part = redfold16(part);
    if (hl == 0) out[b] = part + b2[0];
}

extern "C" void kernel_launch(void* const* d_in, const int* in_sizes, int n_in,
                              void* d_out, int out_size, void* d_ws, size_t ws_size,
                              hipStream_t stream) {
    (void)in_sizes; (void)n_in; (void)out_size; (void)d_ws; (void)ws_size;
    const float* theta = (const float*)d_in[0];
    const float* rotw  = (const float*)d_in[1];
    const float* esc   = (const float*)d_in[2];
    const float* ebi   = (const float*)d_in[3];
    const float* W1    = (const float*)d_in[4];
    const float* b1    = (const float*)d_in[5];
    const float* W2    = (const float*)d_in[6];
    const float* b2    = (const float*)d_in[7];
    float* out = (float*)d_out;

    qrh_kernel<<<BATCH / 8, 256, 0, stream>>>(theta, rotw, esc, ebi, W1, b1, W2, b2, out);
}